// Round 6
// baseline (166.652 us; speedup 1.0000x reference)
//
#include <hip/hip_runtime.h>
#include <math.h>

// ---------------------------------------------------------------------------
// FrameDockingScoreModel — round 14.
//
// r13 post-mortem: code shrink gave 50->45us (10%), not the predicted 40% —
// I$ was a contributor, not the wall. Across r8/r11/r13 each wave is
// VALU-ready only ~14% of its lifetime and ~3 resident waves/SIMD don't
// hide each other -> stalls are CORRELATED. Mechanism: s_load returns are
// OUT OF ORDER on CDNA, so every weight-consuming FMA group needs
// s_waitcnt lgkmcnt(0) — a FULL drain of the s_load queue including all
// prefetch for later groups. No SMEM software pipeline is possible. All
// waves drain at the same program points on the same addresses.
// ds_read returns IN ORDER -> partial lgkmcnt(N) pipelines (m97 asm).
//
// Round-14: stage ws (785 floats, 3.1KB) into LDS once per block, read
// weights as uniform-address ds_read_b128 (broadcast, conflict-free,
// 9 per 36-weight group). Weight values + FMA order unchanged -> bitwise-
// identical to r13. Everything else = r13 (rolled p-loop, named scalars,
// scalar stores). ~190 extra DS insts/item buy an in-order, pipelineable
// weight stream: group g+1's loads fly under group g's 45 FMAs.
// Checks: LDS_Block_Size ~3.3KB; WRITE == 46875 KB; VGPR 80-110.
// Predicted: fd14 24-32us, VALUBusy 55-75%. Falsifier: >=40us @ <=45%
// kills the lgkmcnt-drain theory -> probe input/L3 feed, near-roofline.
// ---------------------------------------------------------------------------

#define K_A   (0.10846522890932808f * 0.24253562503633297f)  // C2_000*C1_000
#define K_B   (0.10846522890932808f * 0.14002800840979312f)  // C2_000*C1_110
#define K_P   (0.06262242910851495f * 0.33333333333333333f)  // C2_110*C1_011
#define K_Q   (0.06262242910851495f * 0.33333333333333333f)  // C2_110*C1_101
#define K_R   (0.06262242910851495f * 0.23570226039551584f)  // C2_110*C1_111
#define K_WB  (0.14907119849998599f * 0.24253562503633297f)  // C2_011*C1_000
#define K_CB  (0.14907119849998599f * 0.14002800840979312f)  // C2_011*C1_110
#define K_WA  (0.14907119849998599f * 0.33333333333333333f)  // C2_101*C1_011
#define K_WBT (0.14907119849998599f * 0.33333333333333333f)  // C2_101*C1_101
#define K_WC  (0.14907119849998599f * 0.23570226039551584f)  // C2_101*C1_111
#define K_WA3 (0.10540925533894598f * 0.33333333333333333f)  // C2_111*C1_011
#define K_WB3 (0.10540925533894598f * 0.33333333333333333f)  // C2_111*C1_101
#define K_WC3 (0.10540925533894598f * 0.23570226039551584f)  // C2_111*C1_111

// ws layout: 80 rows x 9 floats (rows 77..79 zero) = 720, then extras
#define EX_WB   720   // 16
#define EX_CB   736   // 1 (737..739 pad)
#define EX_WA   740   // 16
#define EX_WBT  756   // 16
#define EX_WC   772   // 4
#define EX_WA3  776   // 4
#define EX_WB3  780   // 4
#define EX_WC3  784   // 1
#define N_WS    785

__global__ void fd14_prep(const float* __restrict__ w1_000, const float* __restrict__ w1_110,
                          const float* __restrict__ w1_011, const float* __restrict__ w1_101,
                          const float* __restrict__ w1_111, const float* __restrict__ w2_000,
                          const float* __restrict__ w2_110, const float* __restrict__ w2_011,
                          const float* __restrict__ w2_101, const float* __restrict__ w2_111,
                          float* __restrict__ ws)
{
    int j = blockIdx.x * 256 + threadIdx.x;
    if (j >= N_WS) return;
    float val = 0.f;
    if (j < 720) {
        int r = j / 9, c = j - r * 9;
        if (r < 64) {                       // s1(x)s2(x)s3 rows
            int pq = r >> 2, v = r & 3;
            float a = 0.f;
            for (int u = 0; u < 20; ++u)
                a = fmaf(w1_000[pq * 20 + u], w2_000[u * 36 + v * 9 + c], a);
            val = K_A * a;
        } else if (r < 68) {                // dot12*s3 rows
            int v = r - 64; float a = 0.f;
            for (int u = 0; u < 20; ++u)
                a = fmaf(w1_110[u], w2_000[u * 36 + v * 9 + c], a);
            val = K_B * a;
        } else if (r < 72) {                // d23*s1 rows
            int u = r - 68; float a = 0.f;
            for (int m = 0; m < 5; ++m)
                a = fmaf(w1_011[u * 5 + m], w2_110[m * 9 + c], a);
            val = K_P * a;
        } else if (r < 76) {                // d13*s2 rows
            int u = r - 72; float a = 0.f;
            for (int m = 0; m < 5; ++m)
                a = fmaf(w1_101[u * 5 + m], w2_110[m * 9 + c], a);
            val = K_Q * a;
        } else if (r == 76) {               // dtp row
            float a = 0.f;
            for (int m = 0; m < 5; ++m)
                a = fmaf(w1_111[m], w2_110[m * 9 + c], a);
            val = K_R * a;
        }                                   // rows 77..79: zero
    } else {
        int k = j - 720;
        if (k < 16) {                       // WB[pq]
            float a = 0.f;
            for (int u = 0; u < 20; ++u)
                a = fmaf(w2_011[u], w1_000[k * 20 + u], a);
            val = K_WB * a;
        } else if (k == 16) {               // CB
            float a = 0.f;
            for (int u = 0; u < 20; ++u)
                a = fmaf(w2_011[u], w1_110[u], a);
            val = K_CB * a;
        } else if (k >= 20 && k < 36) {     // WA[u*4+v]
            int u = (k - 20) >> 2, v = (k - 20) & 3;
            float a = 0.f;
            for (int m = 0; m < 5; ++m)
                a = fmaf(w1_011[u * 5 + m], w2_101[m * 4 + v], a);
            val = K_WA * a;
        } else if (k >= 36 && k < 52) {     // WBT[u*4+v]
            int u = (k - 36) >> 2, v = (k - 36) & 3;
            float a = 0.f;
            for (int m = 0; m < 5; ++m)
                a = fmaf(w1_101[u * 5 + m], w2_101[m * 4 + v], a);
            val = K_WBT * a;
        } else if (k >= 52 && k < 56) {     // WC[v]
            int v = k - 52; float a = 0.f;
            for (int m = 0; m < 5; ++m)
                a = fmaf(w1_111[m], w2_101[m * 4 + v], a);
            val = K_WC * a;
        } else if (k >= 56 && k < 60) {     // WA3[u]
            int u = k - 56; float a = 0.f;
            for (int m = 0; m < 5; ++m)
                a = fmaf(w2_111[m], w1_011[u * 5 + m], a);
            val = K_WA3 * a;
        } else if (k >= 60 && k < 64) {     // WB3[v]
            int v = k - 60; float a = 0.f;
            for (int m = 0; m < 5; ++m)
                a = fmaf(w2_111[m], w1_101[v * 5 + m], a);
            val = K_WB3 * a;
        } else if (k == 64) {               // WC3
            float a = 0.f;
            for (int m = 0; m < 5; ++m)
                a = fmaf(w2_111[m], w1_111[m], a);
            val = K_WC3 * a;
        }
    }
    ws[j] = val;
}

__global__ __launch_bounds__(256) void
fd14(const float* __restrict__ lig, const float* __restrict__ rec,
     const float* __restrict__ ws, float* __restrict__ out, int n)
{
    __shared__ float lws[N_WS];

    const int tid = blockIdx.x * 256 + threadIdx.x;
    // Clamp so inactive tail threads issue valid loads (stores are guarded).
    const size_t ci = (size_t)((tid < n) ? tid : (n - 1));

    // Issue input loads FIRST (6 dwordx4 in flight across the staging phase).
    const float4* L = (const float4*)(lig + ci * 12);
    const float4* R = (const float4*)(rec + ci * 12);
    float4 l0 = L[0], l1 = L[1], l2 = L[2];
    float4 r0 = R[0], r1 = R[1], r2 = R[2];

    // Stage the weight table into LDS (once per block; all threads).
    for (int j = threadIdx.x; j < N_WS; j += 256)
        lws[j] = ws[j];
    __syncthreads();

    float e1x = l0.w - r0.w, e1y = l1.x - r1.x, e1z = l1.y - r1.y;
    float e2x = l1.z - r1.z, e2y = l1.w - r1.w, e2z = l2.x - r2.x;
    float e3x = l2.y - r2.y, e3y = l2.z - r2.z, e3z = l2.w - r2.w;

    float n1 = fmaf(e1x, e1x, fmaf(e1y, e1y, e1z * e1z));
    float n2 = fmaf(e2x, e2x, fmaf(e2y, e2y, e2z * e2z));
    float n3sq = fmaf(e3x, e3x, fmaf(e3y, e3y, e3z * e3z));
    float i1 = __builtin_amdgcn_rsqf(n1);
    float i2 = __builtin_amdgcn_rsqf(n2);
    float i3 = __builtin_amdgcn_rsqf(n3sq);
    float d1 = n1 * i1, d2 = n2 * i2, d3 = n3sq * i3;

    float v1x = e1x * i1, v1y = e1y * i1, v1z = e1z * i1;
    float v2x = e2x * i2, v2y = e2y * i2, v2z = e2z * i2;
    float v3x = e3x * i3, v3y = e3y * i3, v3z = e3z * i3;

    const float coeff = -0.18f;
    const float o1 = 1.6666666f, o2 = 3.3333333f, o3 = 5.f;
    float x;
    float s1v0, s1v1, s1v2, s1v3, s2v0, s2v1, s2v2, s2v3, s3v0, s3v1, s3v2, s3v3;
    x = d1;      s1v0 = __expf(coeff * x * x);
    x = d1 - o1; s1v1 = __expf(coeff * x * x);
    x = d1 - o2; s1v2 = __expf(coeff * x * x);
    x = d1 - o3; s1v3 = __expf(coeff * x * x);
    x = d2;      s2v0 = __expf(coeff * x * x);
    x = d2 - o1; s2v1 = __expf(coeff * x * x);
    x = d2 - o2; s2v2 = __expf(coeff * x * x);
    x = d2 - o3; s2v3 = __expf(coeff * x * x);
    x = d3;      s3v0 = __expf(coeff * x * x);
    x = d3 - o1; s3v1 = __expf(coeff * x * x);
    x = d3 - o2; s3v2 = __expf(coeff * x * x);
    x = d3 - o3; s3v3 = __expf(coeff * x * x);

    float dot12 = v1x * v2x + v1y * v2y + v1z * v2z;
    float d13   = v1x * v3x + v1y * v3y + v1z * v3z;
    float d23   = v2x * v3x + v2y * v3y + v2z * v3z;
    float c12x = v1y * v2z - v1z * v2y;
    float c12y = v1z * v2x - v1x * v2z;
    float c12z = v1x * v2y - v1y * v2x;
    float dtp  = c12x * v3x + c12y * v3y + c12z * v3z;

    // ---------------- 77-row matvec, 9 scalar accumulators ----------------
    float acc0 = 0.f, acc1 = 0.f, acc2 = 0.f, acc3 = 0.f, acc4 = 0.f;
    float acc5 = 0.f, acc6 = 0.f, acc7 = 0.f, acc8 = 0.f;

    // One 36-weight group: 9x ds_read_b128 (uniform addr -> broadcast,
    // conflict-free), 36 FMAs in r8's row-major order.
#define GROUPL(abs_, x0v, x1v, x2v, x3v) do { \
    const float x0_ = (x0v), x1_ = (x1v), x2_ = (x2v), x3_ = (x3v); \
    const float4 u0 = *(const float4*)&lws[(abs_) + 0]; \
    const float4 u1 = *(const float4*)&lws[(abs_) + 4]; \
    const float4 u2 = *(const float4*)&lws[(abs_) + 8]; \
    const float4 u3 = *(const float4*)&lws[(abs_) + 12]; \
    const float4 u4 = *(const float4*)&lws[(abs_) + 16]; \
    const float4 u5 = *(const float4*)&lws[(abs_) + 20]; \
    const float4 u6 = *(const float4*)&lws[(abs_) + 24]; \
    const float4 u7 = *(const float4*)&lws[(abs_) + 28]; \
    const float4 u8 = *(const float4*)&lws[(abs_) + 32]; \
    acc0 = fmaf(x0_, u0.x, acc0); acc1 = fmaf(x0_, u0.y, acc1); \
    acc2 = fmaf(x0_, u0.z, acc2); acc3 = fmaf(x0_, u0.w, acc3); \
    acc4 = fmaf(x0_, u1.x, acc4); acc5 = fmaf(x0_, u1.y, acc5); \
    acc6 = fmaf(x0_, u1.z, acc6); acc7 = fmaf(x0_, u1.w, acc7); \
    acc8 = fmaf(x0_, u2.x, acc8); \
    acc0 = fmaf(x1_, u2.y, acc0); acc1 = fmaf(x1_, u2.z, acc1); \
    acc2 = fmaf(x1_, u2.w, acc2); acc3 = fmaf(x1_, u3.x, acc3); \
    acc4 = fmaf(x1_, u3.y, acc4); acc5 = fmaf(x1_, u3.z, acc5); \
    acc6 = fmaf(x1_, u3.w, acc6); acc7 = fmaf(x1_, u4.x, acc7); \
    acc8 = fmaf(x1_, u4.y, acc8); \
    acc0 = fmaf(x2_, u4.z, acc0); acc1 = fmaf(x2_, u4.w, acc1); \
    acc2 = fmaf(x2_, u5.x, acc2); acc3 = fmaf(x2_, u5.y, acc3); \
    acc4 = fmaf(x2_, u5.z, acc4); acc5 = fmaf(x2_, u5.w, acc5); \
    acc6 = fmaf(x2_, u6.x, acc6); acc7 = fmaf(x2_, u6.y, acc7); \
    acc8 = fmaf(x2_, u6.z, acc8); \
    acc0 = fmaf(x3_, u6.w, acc0); acc1 = fmaf(x3_, u7.x, acc1); \
    acc2 = fmaf(x3_, u7.y, acc2); acc3 = fmaf(x3_, u7.z, acc3); \
    acc4 = fmaf(x3_, u7.w, acc4); acc5 = fmaf(x3_, u8.x, acc5); \
    acc6 = fmaf(x3_, u8.y, acc6); acc7 = fmaf(x3_, u8.z, acc7); \
    acc8 = fmaf(x3_, u8.w, acc8); \
} while (0)

    float sg = dot12 * lws[EX_CB];

    // p-loop rolled (r13 I$ win): s1 by register rotation, q unrolled.
    // Group order pq = 0..15 and all chain orders identical to r8.
    {
        int wo = 0;                          // 144 floats per p-iteration
        float s1p = s1v0, s1n1 = s1v1, s1n2 = s1v2, s1n3 = s1v3;
#pragma unroll 1
        for (int p = 0; p < 4; ++p) {
            const float4 wbv = *(const float4*)&lws[EX_WB + 4 * p];
            {
                const float o_ = s1p * s2v0;
                sg = fmaf(o_, wbv.x, sg);
                GROUPL(wo + 0,  o_ * s3v0, o_ * s3v1, o_ * s3v2, o_ * s3v3);
            }
            {
                const float o_ = s1p * s2v1;
                sg = fmaf(o_, wbv.y, sg);
                GROUPL(wo + 36, o_ * s3v0, o_ * s3v1, o_ * s3v2, o_ * s3v3);
            }
            {
                const float o_ = s1p * s2v2;
                sg = fmaf(o_, wbv.z, sg);
                GROUPL(wo + 72, o_ * s3v0, o_ * s3v1, o_ * s3v2, o_ * s3v3);
            }
            {
                const float o_ = s1p * s2v3;
                sg = fmaf(o_, wbv.w, sg);
                GROUPL(wo + 108, o_ * s3v0, o_ * s3v1, o_ * s3v2, o_ * s3v3);
            }
            wo += 144;
            s1p = s1n1; s1n1 = s1n2; s1n2 = s1n3;
        }
    }

    // Tail groups 16..19 (absolute offsets; r8 order).
    GROUPL(576, dot12 * s3v0, dot12 * s3v1, dot12 * s3v2, dot12 * s3v3);
    GROUPL(612, d23 * s1v0, d23 * s1v1, d23 * s1v2, d23 * s1v3);
    GROUPL(648, d13 * s2v0, d13 * s2v1, d13 * s2v2, d13 * s2v3);
    {   // row 76 only (77..79 are zero); 684 is 16B-aligned
        const float4 t0 = *(const float4*)&lws[684];
        const float4 t1 = *(const float4*)&lws[688];
        const float  t2 = lws[692];
        acc0 = fmaf(dtp, t0.x, acc0); acc1 = fmaf(dtp, t0.y, acc1);
        acc2 = fmaf(dtp, t0.z, acc2); acc3 = fmaf(dtp, t0.w, acc3);
        acc4 = fmaf(dtp, t1.x, acc4); acc5 = fmaf(dtp, t1.y, acc5);
        acc6 = fmaf(dtp, t1.z, acc6); acc7 = fmaf(dtp, t1.w, acc7);
        acc8 = fmaf(dtp, t2, acc8);
    }
#undef GROUPL

    // ---------------- epilogue scalars (r8 order, LDS float4 reads) -------
    float ta = 0.f, tb = 0.f;
    {
        const float4 a0 = *(const float4*)&lws[EX_WA + 0];
        const float4 a1 = *(const float4*)&lws[EX_WA + 4];
        const float4 a2 = *(const float4*)&lws[EX_WA + 8];
        const float4 a3 = *(const float4*)&lws[EX_WA + 12];
        const float4 b0 = *(const float4*)&lws[EX_WBT + 0];
        const float4 b1 = *(const float4*)&lws[EX_WBT + 4];
        const float4 b2 = *(const float4*)&lws[EX_WBT + 8];
        const float4 b3 = *(const float4*)&lws[EX_WBT + 12];
        float da, db;
        da = fmaf(a0.x, s3v0, fmaf(a0.y, s3v1, fmaf(a0.z, s3v2, a0.w * s3v3)));
        db = fmaf(b0.x, s3v0, fmaf(b0.y, s3v1, fmaf(b0.z, s3v2, b0.w * s3v3)));
        ta = fmaf(s1v0, da, ta); tb = fmaf(s2v0, db, tb);
        da = fmaf(a1.x, s3v0, fmaf(a1.y, s3v1, fmaf(a1.z, s3v2, a1.w * s3v3)));
        db = fmaf(b1.x, s3v0, fmaf(b1.y, s3v1, fmaf(b1.z, s3v2, b1.w * s3v3)));
        ta = fmaf(s1v1, da, ta); tb = fmaf(s2v1, db, tb);
        da = fmaf(a2.x, s3v0, fmaf(a2.y, s3v1, fmaf(a2.z, s3v2, a2.w * s3v3)));
        db = fmaf(b2.x, s3v0, fmaf(b2.y, s3v1, fmaf(b2.z, s3v2, b2.w * s3v3)));
        ta = fmaf(s1v2, da, ta); tb = fmaf(s2v2, db, tb);
        da = fmaf(a3.x, s3v0, fmaf(a3.y, s3v1, fmaf(a3.z, s3v2, a3.w * s3v3)));
        db = fmaf(b3.x, s3v0, fmaf(b3.y, s3v1, fmaf(b3.z, s3v2, b3.w * s3v3)));
        ta = fmaf(s1v3, da, ta); tb = fmaf(s2v3, db, tb);
    }
    float tc, wa, wb;
    {
        const float4 wcv  = *(const float4*)&lws[EX_WC];
        const float4 wa3v = *(const float4*)&lws[EX_WA3];
        const float4 wb3v = *(const float4*)&lws[EX_WB3];
        tc = fmaf(wcv.x,  s3v0, fmaf(wcv.y,  s3v1, fmaf(wcv.z,  s3v2, wcv.w  * s3v3)));
        wa = fmaf(wa3v.x, s1v0, fmaf(wa3v.y, s1v1, fmaf(wa3v.z, s1v2, wa3v.w * s1v3)));
        wb = fmaf(wb3v.x, s2v0, fmaf(wb3v.y, s2v1, fmaf(wb3v.z, s2v2, wb3v.w * s2v3)));
    }
    float wc = lws[EX_WC3];

    float c23x = v2y * v3z - v2z * v3y;
    float c23y = v2z * v3x - v2x * v3z;
    float c23z = v2x * v3y - v2y * v3x;
    float c13x = v1y * v3z - v1z * v3y;
    float c13y = v1z * v3x - v1x * v3z;
    float c13z = v1x * v3y - v1y * v3x;
    float ccrx = c12y * v3z - c12z * v3y;
    float ccry = c12z * v3x - c12x * v3z;
    float ccrz = c12x * v3y - c12y * v3x;

    float V2x = sg * v3x + ta * v2x + tb * v1x + tc * c12x + wa * c23x + wb * c13x + wc * ccrx;
    float V2y = sg * v3y + ta * v2y + tb * v1y + tc * c12y + wa * c23y + wb * c13y + wc * ccry;
    float V2z = sg * v3z + ta * v2z + tb * v1z + tc * c12z + wa * c23z + wb * c13z + wc * ccrz;

    // ---------------- stores (r8 pattern, guarded) ----------------
    if (tid < n) {
        const size_t n3 = (size_t)n * 3;
        const size_t base = (size_t)tid * 3;
        out[base + 0] = acc0;
        out[base + 1] = acc1;
        out[base + 2] = acc2;
        out[n3 + base + 0] = acc3;
        out[n3 + base + 1] = acc4;
        out[n3 + base + 2] = acc5;
        out[2 * n3 + base + 0] = acc6;
        out[2 * n3 + base + 1] = acc7;
        out[2 * n3 + base + 2] = acc8;
        out[3 * n3 + base + 0] = V2x;
        out[3 * n3 + base + 1] = V2y;
        out[3 * n3 + base + 2] = V2z;
    }
}

extern "C" void kernel_launch(void* const* d_in, const int* in_sizes, int n_in,
                              void* d_out, int out_size, void* d_ws, size_t ws_size,
                              hipStream_t stream) {
    const float* lig = (const float*)d_in[0];
    const float* rec = (const float*)d_in[1];
    float* ws = (float*)d_ws;

    fd14_prep<<<4, 256, 0, stream>>>(
        (const float*)d_in[2], (const float*)d_in[3], (const float*)d_in[4],
        (const float*)d_in[5], (const float*)d_in[6], (const float*)d_in[7],
        (const float*)d_in[8], (const float*)d_in[9], (const float*)d_in[10],
        (const float*)d_in[11], ws);

    int n = in_sizes[0] / 12;
    int blocks = (n + 255) / 256;
    fd14<<<blocks, 256, 0, stream>>>(lig, rec, ws, (float*)d_out, n);
}

// Round 7
// 163.121 us; speedup vs baseline: 1.0216x; 1.0216x over previous
//
#include <hip/hip_runtime.h>
#include <math.h>

// ---------------------------------------------------------------------------
// FrameDockingScoreModel — round 15.
//
// r14 post-mortem: LDS weights were DS-throughput-bound (~190 ds_read/item
// x 61 waves/CU x ~10-12cyc on the shared LDS pipe ~= the whole 108k-cycle
// wall) — the drain-theory test was confounded by its own instrument, and
// VALU busy-time rose 17->24us (ds addressing + float4 movs). Reverted.
//
// Ledger across r8/r11/r13/r14: per-wave issue-busy ~2.1k of ~20k-cycle
// lifetime; VALUBusy ~38% => only ~2.8 resident waves/SIMD. Occupancy has
// been 29-50% in EVERY round despite VGPR 36-56, SGPR 112, LDS 0 allowing
// 8 waves/SIMD. Every prior round tried to make each wave stall less;
// never tried the orthogonal lever: MORE WAVES to cover the stalls. At
// ~10% issue density/wave, even uncorrelated stalls leave the SIMD >60%
// idle with 2.8 waves. Suspected residency limiter: 256-thread workgroup
// dispatch granularity (~3-4 blocks kept in flight per CU).
//
// Round-15: r13 byte-for-byte (bitwise-identical results), ONE change:
// block 256 -> 1024. A 1024-thread block lands 16 waves on a CU
// atomically; VGPR 44 <= 64 allows 2 blocks/CU = 32 waves = 100%. No
// barriers in the body -> block size is semantically inert.
// Checks: VGPR ~44, WRITE == 46875 KB, LDS 0.
// Predicted if residency is the wall: occupancy 60-95%, 28-36us,
// VALUBusy 55-70%. Falsifier: occ >=60% but ~45us -> correlated stalls
// via shared per-CU resource (scalar path) -> r16: weights via per-lane
// VMEM global_load (in-order, vmcnt-pipelineable, L1-resident 3KB).
// ---------------------------------------------------------------------------

#define K_A   (0.10846522890932808f * 0.24253562503633297f)  // C2_000*C1_000
#define K_B   (0.10846522890932808f * 0.14002800840979312f)  // C2_000*C1_110
#define K_P   (0.06262242910851495f * 0.33333333333333333f)  // C2_110*C1_011
#define K_Q   (0.06262242910851495f * 0.33333333333333333f)  // C2_110*C1_101
#define K_R   (0.06262242910851495f * 0.23570226039551584f)  // C2_110*C1_111
#define K_WB  (0.14907119849998599f * 0.24253562503633297f)  // C2_011*C1_000
#define K_CB  (0.14907119849998599f * 0.14002800840979312f)  // C2_011*C1_110
#define K_WA  (0.14907119849998599f * 0.33333333333333333f)  // C2_101*C1_011
#define K_WBT (0.14907119849998599f * 0.33333333333333333f)  // C2_101*C1_101
#define K_WC  (0.14907119849998599f * 0.23570226039551584f)  // C2_101*C1_111
#define K_WA3 (0.10540925533894598f * 0.33333333333333333f)  // C2_111*C1_011
#define K_WB3 (0.10540925533894598f * 0.33333333333333333f)  // C2_111*C1_101
#define K_WC3 (0.10540925533894598f * 0.23570226039551584f)  // C2_111*C1_111

// ws layout: 80 rows x 9 floats (rows 77..79 zero) = 720, then extras
#define EX_WB   720   // 16
#define EX_CB   736   // 1 (737..739 pad)
#define EX_WA   740   // 16
#define EX_WBT  756   // 16
#define EX_WC   772   // 4
#define EX_WA3  776   // 4
#define EX_WB3  780   // 4
#define EX_WC3  784   // 1
#define N_WS    785

__global__ void fd15_prep(const float* __restrict__ w1_000, const float* __restrict__ w1_110,
                          const float* __restrict__ w1_011, const float* __restrict__ w1_101,
                          const float* __restrict__ w1_111, const float* __restrict__ w2_000,
                          const float* __restrict__ w2_110, const float* __restrict__ w2_011,
                          const float* __restrict__ w2_101, const float* __restrict__ w2_111,
                          float* __restrict__ ws)
{
    int j = blockIdx.x * 256 + threadIdx.x;
    if (j >= N_WS) return;
    float val = 0.f;
    if (j < 720) {
        int r = j / 9, c = j - r * 9;
        if (r < 64) {                       // s1(x)s2(x)s3 rows
            int pq = r >> 2, v = r & 3;
            float a = 0.f;
            for (int u = 0; u < 20; ++u)
                a = fmaf(w1_000[pq * 20 + u], w2_000[u * 36 + v * 9 + c], a);
            val = K_A * a;
        } else if (r < 68) {                // dot12*s3 rows
            int v = r - 64; float a = 0.f;
            for (int u = 0; u < 20; ++u)
                a = fmaf(w1_110[u], w2_000[u * 36 + v * 9 + c], a);
            val = K_B * a;
        } else if (r < 72) {                // d23*s1 rows
            int u = r - 68; float a = 0.f;
            for (int m = 0; m < 5; ++m)
                a = fmaf(w1_011[u * 5 + m], w2_110[m * 9 + c], a);
            val = K_P * a;
        } else if (r < 76) {                // d13*s2 rows
            int u = r - 72; float a = 0.f;
            for (int m = 0; m < 5; ++m)
                a = fmaf(w1_101[u * 5 + m], w2_110[m * 9 + c], a);
            val = K_Q * a;
        } else if (r == 76) {               // dtp row
            float a = 0.f;
            for (int m = 0; m < 5; ++m)
                a = fmaf(w1_111[m], w2_110[m * 9 + c], a);
            val = K_R * a;
        }                                   // rows 77..79: zero
    } else {
        int k = j - 720;
        if (k < 16) {                       // WB[pq]
            float a = 0.f;
            for (int u = 0; u < 20; ++u)
                a = fmaf(w2_011[u], w1_000[k * 20 + u], a);
            val = K_WB * a;
        } else if (k == 16) {               // CB
            float a = 0.f;
            for (int u = 0; u < 20; ++u)
                a = fmaf(w2_011[u], w1_110[u], a);
            val = K_CB * a;
        } else if (k >= 20 && k < 36) {     // WA[u*4+v]
            int u = (k - 20) >> 2, v = (k - 20) & 3;
            float a = 0.f;
            for (int m = 0; m < 5; ++m)
                a = fmaf(w1_011[u * 5 + m], w2_101[m * 4 + v], a);
            val = K_WA * a;
        } else if (k >= 36 && k < 52) {     // WBT[u*4+v]
            int u = (k - 36) >> 2, v = (k - 36) & 3;
            float a = 0.f;
            for (int m = 0; m < 5; ++m)
                a = fmaf(w1_101[u * 5 + m], w2_101[m * 4 + v], a);
            val = K_WBT * a;
        } else if (k >= 52 && k < 56) {     // WC[v]
            int v = k - 52; float a = 0.f;
            for (int m = 0; m < 5; ++m)
                a = fmaf(w1_111[m], w2_101[m * 4 + v], a);
            val = K_WC * a;
        } else if (k >= 56 && k < 60) {     // WA3[u]
            int u = k - 56; float a = 0.f;
            for (int m = 0; m < 5; ++m)
                a = fmaf(w2_111[m], w1_011[u * 5 + m], a);
            val = K_WA3 * a;
        } else if (k >= 60 && k < 64) {     // WB3[v]
            int v = k - 60; float a = 0.f;
            for (int m = 0; m < 5; ++m)
                a = fmaf(w2_111[m], w1_101[v * 5 + m], a);
            val = K_WB3 * a;
        } else if (k == 64) {               // WC3
            float a = 0.f;
            for (int m = 0; m < 5; ++m)
                a = fmaf(w2_111[m], w1_111[m], a);
            val = K_WC3 * a;
        }
    }
    ws[j] = val;
}

__global__ __launch_bounds__(1024) void
fd15(const float* __restrict__ lig, const float* __restrict__ rec,
     const float* __restrict__ ws, float* __restrict__ out, int n)
{
    const int tid = blockIdx.x * 1024 + threadIdx.x;
    if (tid >= n) return;

    const float4* L = (const float4*)(lig + (size_t)tid * 12);
    const float4* R = (const float4*)(rec + (size_t)tid * 12);
    float4 l0 = L[0], l1 = L[1], l2 = L[2];
    float4 r0 = R[0], r1 = R[1], r2 = R[2];

    float e1x = l0.w - r0.w, e1y = l1.x - r1.x, e1z = l1.y - r1.y;
    float e2x = l1.z - r1.z, e2y = l1.w - r1.w, e2z = l2.x - r2.x;
    float e3x = l2.y - r2.y, e3y = l2.z - r2.z, e3z = l2.w - r2.w;

    float n1 = fmaf(e1x, e1x, fmaf(e1y, e1y, e1z * e1z));
    float n2 = fmaf(e2x, e2x, fmaf(e2y, e2y, e2z * e2z));
    float n3sq = fmaf(e3x, e3x, fmaf(e3y, e3y, e3z * e3z));
    float i1 = __builtin_amdgcn_rsqf(n1);
    float i2 = __builtin_amdgcn_rsqf(n2);
    float i3 = __builtin_amdgcn_rsqf(n3sq);
    float d1 = n1 * i1, d2 = n2 * i2, d3 = n3sq * i3;

    float v1x = e1x * i1, v1y = e1y * i1, v1z = e1z * i1;
    float v2x = e2x * i2, v2y = e2y * i2, v2z = e2z * i2;
    float v3x = e3x * i3, v3y = e3y * i3, v3z = e3z * i3;

    const float coeff = -0.18f;
    const float o1 = 1.6666666f, o2 = 3.3333333f, o3 = 5.f;
    // Named scalars only — no arrays anywhere (scratch rule #20).
    float x;
    float s1v0, s1v1, s1v2, s1v3, s2v0, s2v1, s2v2, s2v3, s3v0, s3v1, s3v2, s3v3;
    x = d1;      s1v0 = __expf(coeff * x * x);
    x = d1 - o1; s1v1 = __expf(coeff * x * x);
    x = d1 - o2; s1v2 = __expf(coeff * x * x);
    x = d1 - o3; s1v3 = __expf(coeff * x * x);
    x = d2;      s2v0 = __expf(coeff * x * x);
    x = d2 - o1; s2v1 = __expf(coeff * x * x);
    x = d2 - o2; s2v2 = __expf(coeff * x * x);
    x = d2 - o3; s2v3 = __expf(coeff * x * x);
    x = d3;      s3v0 = __expf(coeff * x * x);
    x = d3 - o1; s3v1 = __expf(coeff * x * x);
    x = d3 - o2; s3v2 = __expf(coeff * x * x);
    x = d3 - o3; s3v3 = __expf(coeff * x * x);

    float dot12 = v1x * v2x + v1y * v2y + v1z * v2z;
    float d13   = v1x * v3x + v1y * v3y + v1z * v3z;
    float d23   = v2x * v3x + v2y * v3y + v2z * v3z;
    float c12x = v1y * v2z - v1z * v2y;
    float c12y = v1z * v2x - v1x * v2z;
    float c12z = v1x * v2y - v1y * v2x;
    float dtp  = c12x * v3x + c12y * v3y + c12z * v3z;

    // ---------------- 77-row matvec, 9 scalar accumulators ----------------
    float acc0 = 0.f, acc1 = 0.f, acc2 = 0.f, acc3 = 0.f, acc4 = 0.f;
    float acc5 = 0.f, acc6 = 0.f, acc7 = 0.f, acc8 = 0.f;

#define ROW9(off_, x_) do { \
    const float x9_ = (x_); \
    acc0 = fmaf(x9_, wp[(off_) + 0], acc0); acc1 = fmaf(x9_, wp[(off_) + 1], acc1); \
    acc2 = fmaf(x9_, wp[(off_) + 2], acc2); acc3 = fmaf(x9_, wp[(off_) + 3], acc3); \
    acc4 = fmaf(x9_, wp[(off_) + 4], acc4); acc5 = fmaf(x9_, wp[(off_) + 5], acc5); \
    acc6 = fmaf(x9_, wp[(off_) + 6], acc6); acc7 = fmaf(x9_, wp[(off_) + 7], acc7); \
    acc8 = fmaf(x9_, wp[(off_) + 8], acc8); \
} while (0)

    // One q-group: same per-group FMA order as r8 (rows 0..3, cols 0..8).
#define GROUPQ(qi_, s2q_) do { \
    const float o_ = s1p * (s2q_); \
    sg = fmaf(o_, wbp[qi_], sg); \
    const float x0_ = o_ * s3v0, x1_ = o_ * s3v1, x2_ = o_ * s3v2, x3_ = o_ * s3v3; \
    ROW9(36 * (qi_) + 0,  x0_); \
    ROW9(36 * (qi_) + 9,  x1_); \
    ROW9(36 * (qi_) + 18, x2_); \
    ROW9(36 * (qi_) + 27, x3_); \
} while (0)

    float sg = dot12 * ws[EX_CB];

    // p-loop kept rolled (r13 I$ win): s1 selection by register rotation,
    // q fully unrolled inside. Group order pq = 0..15, chain order = r8.
    {
        const float* wp  = ws;
        const float* wbp = ws + EX_WB;
        float s1p = s1v0, s1n1 = s1v1, s1n2 = s1v2, s1n3 = s1v3;
#pragma unroll 1
        for (int p = 0; p < 4; ++p) {
            GROUPQ(0, s2v0);
            GROUPQ(1, s2v1);
            GROUPQ(2, s2v2);
            GROUPQ(3, s2v3);
            wp += 144;
            wbp += 4;
            s1p = s1n1; s1n1 = s1n2; s1n2 = s1n3;
        }
    }
#undef GROUPQ

    // Tail groups 16..19: straight-line (r8 layout and order).
#define GROUP4T(g, x0v, x1v, x2v, x3v) do { \
    const float* wp = ws + 36 * (g); \
    ROW9(0,  (x0v)); \
    ROW9(9,  (x1v)); \
    ROW9(18, (x2v)); \
    ROW9(27, (x3v)); \
} while (0)

    GROUP4T(16, dot12 * s3v0, dot12 * s3v1, dot12 * s3v2, dot12 * s3v3);
    GROUP4T(17, d23 * s1v0, d23 * s1v1, d23 * s1v2, d23 * s1v3);
    GROUP4T(18, d13 * s2v0, d13 * s2v1, d13 * s2v2, d13 * s2v3);
    {   // row 76 only (77..79 are zero)
        const float* wp = ws + 36 * 19;
        ROW9(0, dtp);
    }
#undef GROUP4T
#undef ROW9

    // ---------------- epilogue scalars (r8) ----------------
    float ta = 0.f, tb = 0.f;
    {
        float da, db;
        da = fmaf(ws[EX_WA + 0],  s3v0, fmaf(ws[EX_WA + 1],  s3v1,
             fmaf(ws[EX_WA + 2],  s3v2, ws[EX_WA + 3]  * s3v3)));
        db = fmaf(ws[EX_WBT + 0], s3v0, fmaf(ws[EX_WBT + 1], s3v1,
             fmaf(ws[EX_WBT + 2], s3v2, ws[EX_WBT + 3] * s3v3)));
        ta = fmaf(s1v0, da, ta); tb = fmaf(s2v0, db, tb);
        da = fmaf(ws[EX_WA + 4],  s3v0, fmaf(ws[EX_WA + 5],  s3v1,
             fmaf(ws[EX_WA + 6],  s3v2, ws[EX_WA + 7]  * s3v3)));
        db = fmaf(ws[EX_WBT + 4], s3v0, fmaf(ws[EX_WBT + 5], s3v1,
             fmaf(ws[EX_WBT + 6], s3v2, ws[EX_WBT + 7] * s3v3)));
        ta = fmaf(s1v1, da, ta); tb = fmaf(s2v1, db, tb);
        da = fmaf(ws[EX_WA + 8],  s3v0, fmaf(ws[EX_WA + 9],  s3v1,
             fmaf(ws[EX_WA + 10], s3v2, ws[EX_WA + 11] * s3v3)));
        db = fmaf(ws[EX_WBT + 8], s3v0, fmaf(ws[EX_WBT + 9], s3v1,
             fmaf(ws[EX_WBT + 10], s3v2, ws[EX_WBT + 11] * s3v3)));
        ta = fmaf(s1v2, da, ta); tb = fmaf(s2v2, db, tb);
        da = fmaf(ws[EX_WA + 12], s3v0, fmaf(ws[EX_WA + 13], s3v1,
             fmaf(ws[EX_WA + 14], s3v2, ws[EX_WA + 15] * s3v3)));
        db = fmaf(ws[EX_WBT + 12], s3v0, fmaf(ws[EX_WBT + 13], s3v1,
             fmaf(ws[EX_WBT + 14], s3v2, ws[EX_WBT + 15] * s3v3)));
        ta = fmaf(s1v3, da, ta); tb = fmaf(s2v3, db, tb);
    }
    float tc = fmaf(ws[EX_WC + 0], s3v0, fmaf(ws[EX_WC + 1], s3v1,
               fmaf(ws[EX_WC + 2], s3v2, ws[EX_WC + 3] * s3v3)));
    float wa = fmaf(ws[EX_WA3 + 0], s1v0, fmaf(ws[EX_WA3 + 1], s1v1,
               fmaf(ws[EX_WA3 + 2], s1v2, ws[EX_WA3 + 3] * s1v3)));
    float wb = fmaf(ws[EX_WB3 + 0], s2v0, fmaf(ws[EX_WB3 + 1], s2v1,
               fmaf(ws[EX_WB3 + 2], s2v2, ws[EX_WB3 + 3] * s2v3)));
    float wc = ws[EX_WC3];

    float c23x = v2y * v3z - v2z * v3y;
    float c23y = v2z * v3x - v2x * v3z;
    float c23z = v2x * v3y - v2y * v3x;
    float c13x = v1y * v3z - v1z * v3y;
    float c13y = v1z * v3x - v1x * v3z;
    float c13z = v1x * v3y - v1y * v3x;
    float ccrx = c12y * v3z - c12z * v3y;
    float ccry = c12z * v3x - c12x * v3z;
    float ccrz = c12x * v3y - c12y * v3x;

    float V2x = sg * v3x + ta * v2x + tb * v1x + tc * c12x + wa * c23x + wb * c13x + wc * ccrx;
    float V2y = sg * v3y + ta * v2y + tb * v1y + tc * c12y + wa * c23y + wb * c13y + wc * ccry;
    float V2z = sg * v3z + ta * v2z + tb * v1z + tc * c12z + wa * c23z + wb * c13z + wc * ccrz;

    // ---------------- stores (r8 pattern) ----------------
    const size_t n3 = (size_t)n * 3;
    const size_t base = (size_t)tid * 3;
    out[base + 0] = acc0;
    out[base + 1] = acc1;
    out[base + 2] = acc2;
    out[n3 + base + 0] = acc3;
    out[n3 + base + 1] = acc4;
    out[n3 + base + 2] = acc5;
    out[2 * n3 + base + 0] = acc6;
    out[2 * n3 + base + 1] = acc7;
    out[2 * n3 + base + 2] = acc8;
    out[3 * n3 + base + 0] = V2x;
    out[3 * n3 + base + 1] = V2y;
    out[3 * n3 + base + 2] = V2z;
}

extern "C" void kernel_launch(void* const* d_in, const int* in_sizes, int n_in,
                              void* d_out, int out_size, void* d_ws, size_t ws_size,
                              hipStream_t stream) {
    const float* lig = (const float*)d_in[0];
    const float* rec = (const float*)d_in[1];
    float* ws = (float*)d_ws;

    fd15_prep<<<4, 256, 0, stream>>>(
        (const float*)d_in[2], (const float*)d_in[3], (const float*)d_in[4],
        (const float*)d_in[5], (const float*)d_in[6], (const float*)d_in[7],
        (const float*)d_in[8], (const float*)d_in[9], (const float*)d_in[10],
        (const float*)d_in[11], ws);

    int n = in_sizes[0] / 12;
    int blocks = (n + 1023) / 1024;
    fd15<<<blocks, 1024, 0, stream>>>(lig, rec, ws, (float*)d_out, n);
}